// Round 1
// baseline (1954.742 us; speedup 1.0000x reference)
//
#include <hip/hip_runtime.h>
#include <stdint.h>

// Problem constants: B=64, S=512, IN_F=HID=OUT_F=1024
typedef __attribute__((ext_vector_type(8))) short short8_t;   // 8 x bf16 MFMA frag
typedef __attribute__((ext_vector_type(4))) float f32x4_t;    // MFMA acc
typedef __attribute__((ext_vector_type(4))) unsigned int u32x4_t;  // 16B tagged line

__device__ __forceinline__ unsigned short f2bf_u(float f) {
  unsigned int u = __float_as_uint(f);
  unsigned int r = (u + 0x7fff + ((u >> 16) & 1)) >> 16;  // RNE
  return (unsigned short)r;
}
__device__ __forceinline__ float bf2f(unsigned short s) {
  return __uint_as_float(((unsigned int)s) << 16);
}
__device__ __forceinline__ short8_t pack8(float4 a, float4 b) {
  short8_t r;
  r[0]=(short)f2bf_u(a.x); r[1]=(short)f2bf_u(a.y); r[2]=(short)f2bf_u(a.z); r[3]=(short)f2bf_u(a.w);
  r[4]=(short)f2bf_u(b.x); r[5]=(short)f2bf_u(b.y); r[6]=(short)f2bf_u(b.z); r[7]=(short)f2bf_u(b.w);
  return r;
}
__device__ __forceinline__ void gl_lds16(const void* g, void* l) {
  __builtin_amdgcn_global_load_lds(
      (const __attribute__((address_space(1))) unsigned int*)g,
      (__attribute__((address_space(3))) unsigned int*)l, 16, 0, 0);
}

// ---------------- prep: x fp32 -> bf16 (8 elems/thread) ----------------
__global__ void k_prep_x(const float* __restrict__ src, unsigned short* __restrict__ dst) {
  int i = blockIdx.x * blockDim.x + threadIdx.x;          // 4194304 threads
  if (i >= 4194304) return;
  const float4* s = (const float4*)src + (size_t)i * 2;
  float4 a = s[0], b = s[1];
  *(short8_t*)(dst + (size_t)i * 8) = pack8(a, b);
}

// ---------------- prep: W_x, W_ho -> bf16 [N][K]; zero hx2 tag lines ----------------
__global__ void k_prep_w(const float* __restrict__ Wih, const float* __restrict__ Who,
                         unsigned short* __restrict__ Wxbf, unsigned short* __restrict__ Whobf,
                         u32x4_t* __restrict__ hx2) {
  int tid = blockIdx.x * blockDim.x + threadIdx.x;        // 262144 threads
  if (tid < 131072) {            // W_x = W_ih[:, 0:1024]
    int n = tid >> 7, c = tid & 127;
    const float* s = Wih + (size_t)n * 2048 + c * 8;
    float4 a = *(const float4*)s, b = *(const float4*)(s + 4);
    *(short8_t*)(Wxbf + (size_t)n * 1024 + c * 8) = pack8(a, b);
  } else {
    int j = tid - 131072;        // W_ho
    int n = j >> 7, c = j & 127;
    const float* s = Who + (size_t)n * 1024 + c * 8;
    float4 a = *(const float4*)s, b = *(const float4*)(s + 4);
    *(short8_t*)(Whobf + (size_t)n * 1024 + c * 8) = pack8(a, b);
  }
  if (tid < 32768) {             // 512KB: 2 slots x 4 g x 16 rank x 16 row x 16 c16
    u32x4_t z; z[0] = 0; z[1] = 0; z[2] = 0; z[3] = 0;
    hx2[tid] = z;
  }
}

// ---------------- GEMM: C[MxN] = A[MxK] @ Bw[NxK]^T + bias, bf16 MFMA ----------------
template <bool OUT_BF16>
__global__ __launch_bounds__(256, 2) void k_gemm_bt(
    const unsigned short* __restrict__ A, const unsigned short* __restrict__ Bw,
    const float* __restrict__ bias, void* __restrict__ Cout) {
  constexpr int K = 1024, N = 1024;
  __shared__ unsigned short sm[8192];   // bytes [0,8K): A-tile, [8K,16K): B-tile
  const int tid = threadIdx.x;
  const int wave = tid >> 6, lane = tid & 63;
  const int tm = blockIdx.y * 128, tn = blockIdx.x * 128;
  const int wm = wave >> 1, wn = wave & 1;

  f32x4_t acc[4][4];
#pragma unroll
  for (int i = 0; i < 4; i++)
#pragma unroll
    for (int j = 0; j < 4; j++) acc[i][j] = (f32x4_t){0.f, 0.f, 0.f, 0.f};

  char* ldsA = (char*)sm;
  char* ldsB = (char*)sm + 8192;
  const int cc = ((lane & 3) ^ ((lane >> 3) & 3)) * 8;  // swizzled k-chunk (elements)
  const int rs = lane >> 2;                             // row within 16-row group

  for (int k0 = 0; k0 < K; k0 += 32) {
    __syncthreads();
#pragma unroll
    for (int c = 0; c < 2; c++) {
      int r0 = c * 64 + wave * 16;                      // wave-uniform
      int r = r0 + rs;
      gl_lds16(A + (size_t)(tm + r) * K + (k0 + cc), ldsA + r0 * 64);
      gl_lds16(Bw + (size_t)(tn + r) * K + (k0 + cc), ldsB + r0 * 64);
    }
    __builtin_amdgcn_s_waitcnt(0);
    __syncthreads();

    short8_t af[4], bf[4];
#pragma unroll
    for (int mt = 0; mt < 4; mt++) {
      int r = wm * 64 + mt * 16 + (lane & 15);
      int slot = (((lane >> 4) ^ (((lane & 15) >> 1) & 3))) * 16;
      af[mt] = *(const short8_t*)(ldsA + r * 64 + slot);
    }
#pragma unroll
    for (int nt = 0; nt < 4; nt++) {
      int r = wn * 64 + nt * 16 + (lane & 15);
      int slot = (((lane >> 4) ^ (((lane & 15) >> 1) & 3))) * 16;
      bf[nt] = *(const short8_t*)(ldsB + r * 64 + slot);
    }
#pragma unroll
    for (int mt = 0; mt < 4; mt++)
#pragma unroll
      for (int nt = 0; nt < 4; nt++)
        acc[mt][nt] = __builtin_amdgcn_mfma_f32_16x16x32_bf16(af[mt], bf[nt], acc[mt][nt], 0, 0, 0);
  }

#pragma unroll
  for (int nt = 0; nt < 4; nt++) {
    int n = tn + wn * 64 + nt * 16 + (lane & 15);
    float bs = bias[n];
#pragma unroll
    for (int mt = 0; mt < 4; mt++) {
      int rowb = tm + wm * 64 + mt * 16 + ((lane >> 4) << 2);
      f32x4_t v = acc[mt][nt];
#pragma unroll
      for (int q = 0; q < 4; q++) {
        float o = v[q] + bs;
        size_t off = (size_t)(rowb + q) * N + n;
        if (OUT_BF16) ((unsigned short*)Cout)[off] = f2bf_u(o);
        else          ((float*)Cout)[off] = o;
      }
    }
  }
}

// ---------------- persistent recurrence ----------------
// 64 blocks x 256 thr. 4 groups x 16 ranks; group g owns batches [16g,16g+16).
// Cross-CU h exchange via single-transaction 16B tagged lines at LLC:
//   line = [d0, tag, d1, tag], tag = t+1, stored with one global_store_dwordx4
//   sc0 sc1. Consumers poll the data lines directly (batched dwordx4 sc0 sc1
//   loads, one vmcnt(0)) and accept when BOTH tag dwords match. This fuses
//   data+flag: no store-ack drain before a flag, no separate flag round-trip.
//   Each 8B half is self-validating, so only 8B atomicity is assumed.
// 2 slots (t&1): producer can only overwrite slot holding h[t] after its step
// t+2 poll, which requires every rank published h[t+1], which requires every
// rank consumed h[t] -> no lost generations, no ABA (tags strictly increase).
__global__ __launch_bounds__(256, 1) void k_rnn(
    const float* __restrict__ Wih, const float* __restrict__ h0,
    const unsigned short* __restrict__ xproj, unsigned short* __restrict__ Hall,
    char* __restrict__ hx2) {
  const int bid = blockIdx.x;
  const int g = (bid & 7) >> 1;                    // group 0..3
  const int rank = ((bid >> 3) << 1) | (bid & 1);  // 0..15 within group
  const int tid = threadIdx.x;
  const int wave = tid >> 6, lane = tid & 63;
  const int nw = rank * 64 + wave * 16;            // wave's first hidden row (global n)
  const int b0 = g * 16;

  __shared__ unsigned short hs[16][1032];          // h[t-1], full 1024 n, +8 pad
  __shared__ unsigned short hsOut[16][68];         // this CU's 64 n-cols of h[t]

  short8_t bfrag[32];                              // 128 VGPRs of W_h (bf16)
  {
    const int n = nw + (lane & 15);
    const float* wrow = Wih + (size_t)n * 2048 + 1024 + ((lane >> 4) * 8);
#pragma unroll
    for (int kt = 0; kt < 32; kt++) {
      float4 f0 = *(const float4*)(wrow + kt * 32);
      float4 f1 = *(const float4*)(wrow + kt * 32 + 4);
      bfrag[kt] = pack8(f0, f1);
    }
  }

  const int row = tid >> 4, c16 = tid & 15;
  // hx2 byte layout: slot*262144 + g*65536 + rank*4096 + row*256 + c16*16
  const char* hxb = hx2 + g * 65536;               // wave-uniform -> SGPR base
  const unsigned voffc = (unsigned)(row * 256 + c16 * 16);

  for (int t = 0; t < 512; t++) {
    // ---- xproj prefetch (normal loads; latency overlaps the poll RT) ----
    unsigned short xr[4];
#pragma unroll
    for (int q = 0; q < 4; q++) {
      int b = b0 + ((lane >> 4) << 2) + q;
      xr[q] = xproj[((size_t)b * 512 + t) * 1024 + nw + (lane & 15)];
    }

    if (t > 0) {
      // own 64-col chunk: LDS -> LDS (never through global)
      *(unsigned long long*)&hs[row][(rank * 16 + c16) * 4] =
          *(const unsigned long long*)&hsOut[row][c16 * 4];
      const unsigned tg = (unsigned)t;                  // h[t-1] carries tag t
      const unsigned so = ((t - 1) & 1) ? 262144u : 0u; // slot byte offset
      unsigned done = 1u << rank;
      u32x4_t r[16];
#pragma unroll
      for (int j = 0; j < 16; j++) { r[j][0] = 0; r[j][1] = 0; r[j][2] = 0; r[j][3] = 0; }
      while (done != 0xFFFFu) {
#pragma unroll
        for (int j = 0; j < 16; j++) {
          if (!((done >> j) & 1)) {
            asm volatile("global_load_dwordx4 %0, %1, %2 sc0 sc1"
                         : "=v"(r[j])
                         : "v"(so + (unsigned)(j << 12) + voffc), "s"(hxb)
                         : "memory");
          }
        }
        // tie all line regs to the wait so tag checks can't be hoisted
        asm volatile("s_waitcnt vmcnt(0)"
                     : "+v"(r[0]), "+v"(r[1]), "+v"(r[2]), "+v"(r[3]),
                       "+v"(r[4]), "+v"(r[5]), "+v"(r[6]), "+v"(r[7]),
                       "+v"(r[8]), "+v"(r[9]), "+v"(r[10]), "+v"(r[11]),
                       "+v"(r[12]), "+v"(r[13]), "+v"(r[14]), "+v"(r[15]));
#pragma unroll
        for (int j = 0; j < 16; j++) {
          if (!((done >> j) & 1) && r[j][1] == tg && r[j][3] == tg) {
            *(unsigned long long*)&hs[row][(j * 16 + c16) * 4] =
                (unsigned long long)r[j][0] | ((unsigned long long)r[j][2] << 32);
            done |= 1u << j;
          }
        }
      }
    } else {
      const float* s = h0 + (size_t)(b0 + row) * 1024 + c16 * 8;
#pragma unroll
      for (int j = 0; j < 8; j++) {
        float4 a = *(const float4*)(s + j * 128);
        float4 b = *(const float4*)(s + j * 128 + 4);
        *(short8_t*)&hs[row][c16 * 8 + j * 128] = pack8(a, b);
      }
    }
    __syncthreads();

    // ---- MFMA: h[t-1] @ W_h^T for this CU's 16 n-cols per wave ----
    f32x4_t acc0 = {0.f, 0.f, 0.f, 0.f}, acc1 = {0.f, 0.f, 0.f, 0.f};
    {
      const char* abase = (const char*)&hs[lane & 15][0] + ((lane >> 4) * 16);
#pragma unroll
      for (int kt = 0; kt < 32; kt += 2) {
        short8_t a0 = *(const short8_t*)(abase + kt * 64);
        acc0 = __builtin_amdgcn_mfma_f32_16x16x32_bf16(a0, bfrag[kt], acc0, 0, 0, 0);
        short8_t a1 = *(const short8_t*)(abase + (kt + 1) * 64);
        acc1 = __builtin_amdgcn_mfma_f32_16x16x32_bf16(a1, bfrag[kt + 1], acc1, 0, 0, 0);
      }
    }

    // ---- tanh epilogue -> LDS (coalesced 8B stores + next-step self-copy) ----
#pragma unroll
    for (int q = 0; q < 4; q++) {
      int bl = ((lane >> 4) << 2) + q;                     // batch within group
      float p = acc0[q] + acc1[q] + bf2f(xr[q]);
      float e = __expf(2.0f * p);
      float th = 1.0f - 2.0f / (e + 1.0f);                 // tanh
      hsOut[bl][wave * 16 + (lane & 15)] = f2bf_u(th);
    }
    __syncthreads();

    // ---- publish: Hall (normal) + tagged 16B line (fire-and-forget) ----
    {
      unsigned long long vv = *(const unsigned long long*)&hsOut[row][c16 * 4];
      size_t hall_off = ((size_t)(b0 + row) * 512 + t) * 1024 + rank * 64 + c16 * 4;
      *(unsigned long long*)(Hall + hall_off) = vv;
      u32x4_t line;
      line[0] = (unsigned)vv;         line[1] = (unsigned)(t + 1);
      line[2] = (unsigned)(vv >> 32); line[3] = (unsigned)(t + 1);
      const unsigned sow = (t & 1) ? 262144u : 0u;
      asm volatile("global_store_dwordx4 %0, %1, %2 sc0 sc1"
                   :: "v"(sow + (unsigned)(rank << 12) + voffc), "v"(line), "s"(hxb)
                   : "memory");
    }
    // no trailing barrier, no store-ack drain, no flag store
  }
}

// ---------------- launch ----------------
extern "C" void kernel_launch(void* const* d_in, const int* in_sizes, int n_in,
                              void* d_out, int out_size, void* d_ws, size_t ws_size,
                              hipStream_t stream) {
  const float* x   = (const float*)d_in[0];   // 64x512x1024
  const float* h0  = (const float*)d_in[1];   // 64x1024
  const float* Wih = (const float*)d_in[2];   // 1024x2048
  const float* bih = (const float*)d_in[3];   // 1024
  const float* Who = (const float*)d_in[4];   // 1024x1024
  const float* bho = (const float*)d_in[5];   // 1024

  char* ws = (char*)d_ws;
  unsigned short* Xbf   = (unsigned short*)ws;                 // 64MB (dead after GEMM1)
  unsigned short* Hall  = (unsigned short*)ws;                 // aliases Xbf
  unsigned short* xproj = (unsigned short*)(ws + 67108864);    // 64MB
  unsigned short* Wxbf  = (unsigned short*)(ws + 134217728);   // 2MB
  unsigned short* Whobf = (unsigned short*)(ws + 136314880);   // 2MB
  char*           hx2   = ws + 138412032;                      // 512KB tagged lines

  k_prep_x<<<16384, 256, 0, stream>>>(x, Xbf);
  k_prep_w<<<1024, 256, 0, stream>>>(Wih, Who, Wxbf, Whobf, (u32x4_t*)hx2);
  k_gemm_bt<true ><<<dim3(8, 256), 256, 0, stream>>>(Xbf, Wxbf, bih, (void*)xproj);
  k_rnn<<<64, 256, 0, stream>>>(Wih, h0, xproj, Hall, hx2);
  k_gemm_bt<false><<<dim3(8, 256), 256, 0, stream>>>(Hall, Whobf, bho, d_out);
}